// Round 11
// baseline (356.957 us; speedup 1.0000x reference)
//
#include <hip/hip_runtime.h>
#include <hip/hip_bf16.h>

// Problem constants (from setup_inputs)
#define TT 4
#define WAYN 5
#define SHOTN 5
#define WQN 75          // way*query = 5*15
#define CC 640
#define HWN 100
#define YN 500          // shot*hw
#define YPADN 512
#define XPADN 112       // 100 padded to 7*16
#define KT 64           // K chunk
#define NKC 10          // CC/KT

typedef __attribute__((ext_vector_type(8))) short bf16x8;
typedef __attribute__((ext_vector_type(4))) float f32x4;

__device__ __forceinline__ unsigned short f2bf(float f) {
  unsigned int u = __float_as_uint(f);
  u += 0x7fffu + ((u >> 16) & 1u);   // RNE
  return (unsigned short)(u >> 16);
}

// branchless insert of v into sorted triple t1>=t2>=t3
__device__ __forceinline__ void ins3(float v, float& t1, float& t2, float& t3) {
  float a1 = fmaxf(t1, v), d1 = fminf(t1, v);
  float a2 = fmaxf(t2, d1), d2 = fminf(t2, d1);
  float a3 = fmaxf(t3, d2);
  t1 = a1; t2 = a2; t3 = a3;
}

// ---------- prep kernels: build swizzled bf16 operand images in ws ----------

// A image: per (tq, kci): [112 rows][64 k] bf16, elem (xx,kk) at kk^((xx&7)*8),
// value = q[tq, kc+kk, xx] * qinv[tq, kc+kk]; rows 100..111 zero.
__global__ __launch_bounds__(256)
void dn4_prepA(const float* __restrict__ q, unsigned short* __restrict__ Aswz) {
  __shared__ float qls[KT * 105];
  __shared__ float qpart[4][KT];
  __shared__ float qinvls[KT];
  int b = blockIdx.x;            // tq*NKC + kci
  int kci = b % NKC, tq = b / NKC;
  int tid = threadIdx.x;
  const float* qb = q + (size_t)tq * (CC * HWN) + (size_t)kci * KT * HWN;
  #pragma unroll
  for (int i = 0; i < 25; ++i) {     // 6400 contiguous floats, coalesced
    int idx = tid + i * 256;
    int c = idx / 100, x = idx - c * 100;
    qls[c * 105 + x] = qb[idx];
  }
  __syncthreads();
  {                                   // per-c sumsq over 100 x, 4-way split
    int c = tid & 63, qtr = tid >> 6;
    float ss = 0.f;
    const float* r = &qls[c * 105 + qtr * 25];
    #pragma unroll
    for (int j = 0; j < 25; ++j) { float v = r[j]; ss += v * v; }
    qpart[qtr][c] = ss;
  }
  __syncthreads();
  if (tid < KT) {
    float tot = qpart[0][tid] + qpart[1][tid] + qpart[2][tid] + qpart[3][tid];
    qinvls[tid] = 1.f / fmaxf(sqrtf(tot), 1e-12f);
  }
  __syncthreads();
  unsigned short* ob = Aswz + (size_t)b * (XPADN * KT);
  #pragma unroll
  for (int i = 0; i < 4; ++i) {
    int slot = tid + i * 256;        // 896 slots of (xx, kgroup)
    if (slot < XPADN * 8) {
      int xx = slot >> 3, kg = slot & 7;
      bf16x8 v = (bf16x8){0, 0, 0, 0, 0, 0, 0, 0};
      if (xx < HWN) {
        #pragma unroll
        for (int j = 0; j < 8; ++j) {
          int kk = kg * 8 + j;
          v[j] = (short)f2bf(qls[kk * 105 + xx] * qinvls[kk]);
        }
      }
      *(bf16x8*)&ob[xx * KT + ((kg * 8) ^ ((xx & 7) * 8))] = v;
    }
  }
}

// B image: per (tw, kci, shot): rows shot*100..shot*100+99 of the [512][64] image.
// elem (y,kk) at kk^((y&7)*8). Shot-parallel (1000 blocks). shot==0 zero-pads 500..511.
// Also emits ssqpart[(tw*NKC+kci)*YPADN + shot*100+pos].
__global__ __launch_bounds__(256)
void dn4_prepB(const float* __restrict__ s, unsigned short* __restrict__ Bswz,
               float* __restrict__ ssqpart) {
  __shared__ float sls[KT * 105];
  int b = blockIdx.x;            // ((tw*NKC + kci)*SHOTN) + shot
  int shot = b % SHOTN;
  int bb = b / SHOTN;            // tw*NKC + kci
  int kci = bb % NKC, tw = bb / NKC;
  int tid = threadIdx.x;
  unsigned short* ob = Bswz + (size_t)bb * (YPADN * KT);
  float* sqb = ssqpart + (size_t)bb * YPADN;
  const float* sb = s + ((size_t)(tw * SHOTN + shot) * CC + (size_t)kci * KT) * HWN;
  #pragma unroll
  for (int i = 0; i < 25; ++i) {
    int idx = tid + i * 256;
    int c = idx / 100, x = idx - c * 100;
    sls[c * 105 + x] = sb[idx];
  }
  __syncthreads();
  #pragma unroll
  for (int i = 0; i < 4; ++i) {
    int slot = tid + i * 256;      // 800 slots of (pos, kgroup)
    if (slot < HWN * 8) {
      int pos = slot >> 3, kg = slot & 7;
      int y = shot * HWN + pos;
      bf16x8 v;
      #pragma unroll
      for (int j = 0; j < 8; ++j)
        v[j] = (short)f2bf(sls[(kg * 8 + j) * 105 + pos]);
      *(bf16x8*)&ob[y * KT + ((kg * 8) ^ ((y & 7) * 8))] = v;
    }
  }
  if (tid < HWN) {                 // sumsq over this chunk's 64 c's
    float ss = 0.f;
    #pragma unroll
    for (int c = 0; c < KT; ++c) { float v = sls[c * 105 + tid]; ss += v * v; }
    sqb[shot * HWN + tid] = ss;
  }
  if (shot == 0 && tid < (YPADN - YN) * 8) {   // zero pad rows 500..511
    int yy = YN + (tid >> 3), kg = tid & 7;
    *(bf16x8*)&ob[yy * KT + ((kg * 8) ^ ((yy & 7) * 8))] = (bf16x8){0,0,0,0,0,0,0,0};
  }
}

// reduce ssqpart over kci -> sinv[tw][y]
__global__ void dn4_sinv2(const float* __restrict__ ssqpart, float* __restrict__ sinv) {
  int tw = blockIdx.x, y = threadIdx.x;
  if (y < YN) {
    float tot = 0.f;
    #pragma unroll
    for (int k = 0; k < NKC; ++k) tot += ssqpart[((size_t)tw * NKC + k) * YPADN + y];
    sinv[tw * YN + y] = 1.f / fmaxf(sqrtf(tot), 1e-12f);
  }
}

// ---- fallback-path helpers (round-3 verified) ----
__global__ void dn4_sinv(const float* __restrict__ s, float* __restrict__ sinv) {
  __shared__ float ps[4][128];
  int b = blockIdx.x;
  int cg = threadIdx.x >> 7, pos = threadIdx.x & 127;
  float ss = 0.f;
  if (pos < HWN) {
    const float* p = s + ((size_t)b * CC + cg * 160) * HWN + pos;
    #pragma unroll 8
    for (int c = 0; c < 160; ++c) { float v = p[c * HWN]; ss += v * v; }
  }
  ps[cg][pos] = ss;
  __syncthreads();
  if (cg == 0 && pos < HWN) {
    float tot = ps[0][pos] + ps[1][pos] + ps[2][pos] + ps[3][pos];
    int t = b / 25, sidx = b % 25, way = sidx / 5, shot = sidx % 5;
    sinv[(t * WAYN + way) * YN + shot * HWN + pos] = 1.f / fmaxf(sqrtf(tot), 1e-12f);
  }
}

__global__ void dn4_qinv(const float* __restrict__ q, float* __restrict__ qinv) {
  int row = blockIdx.x * 4 + (threadIdx.x >> 6);
  int lane = threadIdx.x & 63;
  const float* p = q + (size_t)row * HWN;
  float ss = 0.f;
  if (lane < 50) { float2 v = ((const float2*)p)[lane]; ss = v.x * v.x + v.y * v.y; }
  #pragma unroll
  for (int off = 32; off; off >>= 1) ss += __shfl_down(ss, off);
  if (lane == 0) qinv[row] = 1.f / fmaxf(sqrtf(ss), 1e-12f);
}

// ---------- main kernel: register-direct MFMA operands (no LDS staging) ----------
// A fragments are identical across all 8 waves -> L1 hits; B slices are per-wave,
// L2-resident per XCD via the bijective XCD swizzle. No barriers in the K-loop.
__global__ __launch_bounds__(512, 2)
void dn4_main(const unsigned short* __restrict__ Aswz,
              const unsigned short* __restrict__ Bswz,
              const float* __restrict__ sinv, float* __restrict__ out) {
  __shared__ float p3[8 * XPADN * 3];      // epilogue only (~11 KB LDS total)
  __shared__ float rowsum[XPADN];

  // bijective XCD swizzle (nwg=1500, nxcd=8 -> q=187, r=4): same-XCD blocks get
  // consecutive wgid -> consecutive (tw,wq) -> shared B panel in that XCD's L2.
  int orig = blockIdx.x;
  int xcd = orig & 7;
  int idx = orig >> 3;
  int wgid = (xcd < 4 ? xcd * 188 : 752 + (xcd - 4) * 187) + idx;

  int wq = wgid % WQN;
  int tw = wgid / WQN;          // t*WAYN + way
  int t = tw / WAYN;
  int way = tw % WAYN;
  int tq = t * WQN + wq;

  int tid = threadIdx.x;
  int lane = tid & 63;
  int wv = tid >> 6;            // wave owns y-slice [64*wv, 64*wv+64)
  int m = lane & 15, g = lane >> 4;

  const unsigned short* gA = Aswz + (size_t)tq * (NKC * XPADN * KT);
  const unsigned short* gB = Bswz + (size_t)tw * (NKC * YPADN * KT) + (size_t)(wv * 64) * KT;
  const float* sinvb = sinv + tw * YN;

  f32x4 acc[7][4];
  #pragma unroll
  for (int i = 0; i < 7; ++i)
    #pragma unroll
    for (int j = 0; j < 4; ++j) acc[i][j] = (f32x4){0.f, 0.f, 0.f, 0.f};

  for (int kci = 0; kci < NKC; ++kci) {
    const unsigned short* aC = gA + kci * (XPADN * KT);
    const unsigned short* bC = gB + kci * (YPADN * KT);
    #pragma unroll
    for (int ks = 0; ks < 2; ++ks) {
      int colb = (ks * 32 + g * 8) ^ ((m & 7) * 8);
      bf16x8 af[7];
      #pragma unroll
      for (int ti = 0; ti < 7; ++ti)
        af[ti] = *(const bf16x8*)&aC[(ti * 16 + m) * KT + colb];
      #pragma unroll
      for (int tj = 0; tj < 4; ++tj) {
        bf16x8 bfr = *(const bf16x8*)&bC[(tj * 16 + m) * KT + colb];
        #pragma unroll
        for (int ti = 0; ti < 7; ++ti)
          acc[ti][tj] = __builtin_amdgcn_mfma_f32_16x16x32_bf16(af[ti], bfr, acc[ti][tj], 0, 0, 0);
      }
    }
  }

  // ---- fused top-3 over y per row x, then sum over rows ----
  // D layout: col(y)=lane&15, row(x)=4*(lane>>4)+reg
  float sv[4];
  #pragma unroll
  for (int tj = 0; tj < 4; ++tj) {
    int y = wv * 64 + tj * 16 + m;
    sv[tj] = (y < YN) ? sinvb[y] : 0.f;
  }
  const float NEG = -1e30f;
  #pragma unroll
  for (int ti = 0; ti < 7; ++ti) {
    #pragma unroll
    for (int r = 0; r < 4; ++r) {
      float t1 = NEG, t2 = NEG, t3 = NEG;
      #pragma unroll
      for (int tj = 0; tj < 4; ++tj) {
        int y = wv * 64 + tj * 16 + m;
        float v = (y < YN) ? acc[ti][tj][r] * sv[tj] : NEG;
        ins3(v, t1, t2, t3);
      }
      #pragma unroll
      for (int msk = 1; msk < 16; msk <<= 1) {
        float o1 = __shfl_xor(t1, msk);
        float o2 = __shfl_xor(t2, msk);
        float o3 = __shfl_xor(t3, msk);
        ins3(o1, t1, t2, t3);
        ins3(o2, t1, t2, t3);
        ins3(o3, t1, t2, t3);
      }
      if (m == 0) {
        int x = ti * 16 + g * 4 + r;
        p3[(wv * XPADN + x) * 3 + 0] = t1;
        p3[(wv * XPADN + x) * 3 + 1] = t2;
        p3[(wv * XPADN + x) * 3 + 2] = t3;
      }
    }
  }
  __syncthreads();
  if (tid < XPADN) {
    float t1 = NEG, t2 = NEG, t3 = NEG;
    #pragma unroll
    for (int w = 0; w < 8; ++w) {
      ins3(p3[(w * XPADN + tid) * 3 + 0], t1, t2, t3);
      ins3(p3[(w * XPADN + tid) * 3 + 1], t1, t2, t3);
      ins3(p3[(w * XPADN + tid) * 3 + 2], t1, t2, t3);
    }
    rowsum[tid] = (tid < HWN) ? (t1 + t2 + t3) : 0.f;
  }
  __syncthreads();
  if (tid < 64) {
    float sres = rowsum[tid] + ((tid + 64 < XPADN) ? rowsum[tid + 64] : 0.f);
    #pragma unroll
    for (int off = 32; off; off >>= 1) sres += __shfl_down(sres, off);
    if (tid == 0) out[tq * WAYN + way] = sres;
  }
}

// ---------- fallback: round-3 verified all-in-one kernel ----------
__global__ __launch_bounds__(512, 2)
void dn4_main_fb(const float* __restrict__ q, const float* __restrict__ s,
                 const float* __restrict__ qinv, const float* __restrict__ sinv,
                 float* __restrict__ out) {
  __shared__ __align__(16) unsigned short aT[XPADN * 64];
  __shared__ __align__(16) unsigned short bT[YPADN * 64];
  __shared__ float part3[8][XPADN][3];
  __shared__ float rowsum[XPADN];

  int bid = blockIdx.x;
  int wq = bid % WQN;
  int tw = bid / WQN;
  int way = tw % WAYN;
  int t = tw / WAYN;

  int tid = threadIdx.x;
  int lane = tid & 63;
  int wv = tid >> 6;
  int m = lane & 15, g = lane >> 4;

  const float* qb = q + ((size_t)(t * WQN + wq) * CC) * HWN;
  const float* sb = s + ((size_t)(t * 25 + way * SHOTN) * CC) * HWN;
  const float* qinvb = qinv + (t * WQN + wq) * CC;
  const float* sinvb = sinv + (t * WAYN + way) * YN;

  f32x4 acc[7][4];
  #pragma unroll
  for (int i = 0; i < 7; ++i)
    #pragma unroll
    for (int j = 0; j < 4; ++j) acc[i][j] = (f32x4){0.f, 0.f, 0.f, 0.f};

  for (int kc = 0; kc < CC; kc += KT) {
    __syncthreads();
    #pragma unroll
    for (int it = 0; it < 16; ++it) {
      int e = tid + it * 512;
      int kk = e >> 7, xx = e & 127;
      if (xx < XPADN) {
        float v = 0.f;
        if (xx < HWN) v = qb[(kc + kk) * HWN + xx] * qinvb[kc + kk];
        aT[xx * 64 + (kk ^ ((xx & 7) * 8))] = f2bf(v);
      }
    }
    #pragma unroll
    for (int it = 0; it < 16; ++it) {
      int e = tid + it * 512;
      int kk = e >> 7, yg = e & 127;
      int y0 = yg * 4;
      float4 v = make_float4(0.f, 0.f, 0.f, 0.f);
      if (y0 < YN) {
        int shot = (y0 * 41) >> 12;
        int pos = y0 - shot * HWN;
        v = *(const float4*)&sb[((size_t)shot * CC + (kc + kk)) * HWN + pos];
      }
      bT[(y0 + 0) * 64 + (kk ^ (((y0 + 0) & 7) * 8))] = f2bf(v.x);
      bT[(y0 + 1) * 64 + (kk ^ (((y0 + 1) & 7) * 8))] = f2bf(v.y);
      bT[(y0 + 2) * 64 + (kk ^ (((y0 + 2) & 7) * 8))] = f2bf(v.z);
      bT[(y0 + 3) * 64 + (kk ^ (((y0 + 3) & 7) * 8))] = f2bf(v.w);
    }
    __syncthreads();
    #pragma unroll
    for (int ks = 0; ks < 2; ++ks) {
      int colb = (ks * 32 + g * 8) ^ ((m & 7) * 8);
      bf16x8 af[7];
      #pragma unroll
      for (int ti = 0; ti < 7; ++ti)
        af[ti] = *(const bf16x8*)&aT[(ti * 16 + m) * 64 + colb];
      #pragma unroll
      for (int tj = 0; tj < 4; ++tj) {
        bf16x8 bfr = *(const bf16x8*)&bT[(wv * 64 + tj * 16 + m) * 64 + colb];
        #pragma unroll
        for (int ti = 0; ti < 7; ++ti)
          acc[ti][tj] = __builtin_amdgcn_mfma_f32_16x16x32_bf16(af[ti], bfr, acc[ti][tj], 0, 0, 0);
      }
    }
  }

  float sv[4];
  #pragma unroll
  for (int tj = 0; tj < 4; ++tj) {
    int y = wv * 64 + tj * 16 + m;
    sv[tj] = (y < YN) ? sinvb[y] : 0.f;
  }
  const float NEG = -1e30f;
  #pragma unroll
  for (int ti = 0; ti < 7; ++ti) {
    #pragma unroll
    for (int r = 0; r < 4; ++r) {
      float t1 = NEG, t2 = NEG, t3 = NEG;
      #pragma unroll
      for (int tj = 0; tj < 4; ++tj) {
        int y = wv * 64 + tj * 16 + m;
        float v = (y < YN) ? acc[ti][tj][r] * sv[tj] : NEG;
        ins3(v, t1, t2, t3);
      }
      #pragma unroll
      for (int msk = 1; msk < 16; msk <<= 1) {
        float o1 = __shfl_xor(t1, msk);
        float o2 = __shfl_xor(t2, msk);
        float o3 = __shfl_xor(t3, msk);
        ins3(o1, t1, t2, t3);
        ins3(o2, t1, t2, t3);
        ins3(o3, t1, t2, t3);
      }
      if (m == 0) {
        int x = ti * 16 + g * 4 + r;
        part3[wv][x][0] = t1; part3[wv][x][1] = t2; part3[wv][x][2] = t3;
      }
    }
  }
  __syncthreads();
  if (tid < XPADN) {
    float t1 = NEG, t2 = NEG, t3 = NEG;
    #pragma unroll
    for (int w = 0; w < 8; ++w) {
      ins3(part3[w][tid][0], t1, t2, t3);
      ins3(part3[w][tid][1], t1, t2, t3);
      ins3(part3[w][tid][2], t1, t2, t3);
    }
    rowsum[tid] = (tid < HWN) ? (t1 + t2 + t3) : 0.f;
  }
  __syncthreads();
  if (tid < 64) {
    float sres = rowsum[tid] + ((tid + 64 < XPADN) ? rowsum[tid + 64] : 0.f);
    #pragma unroll
    for (int off = 32; off; off >>= 1) sres += __shfl_down(sres, off);
    if (tid == 0) out[(t * WQN + wq) * WAYN + way] = sres;
  }
}

extern "C" void kernel_launch(void* const* d_in, const int* in_sizes, int n_in,
                              void* d_out, int out_size, void* d_ws, size_t ws_size,
                              hipStream_t stream) {
  const float* q = (const float*)d_in[0];
  const float* s = (const float*)d_in[1];
  float* out = (float*)d_out;

  // main-path ws layout:
  //   sinv    f32[10000]        @ 0        (40000 B)
  //   ssqpart f32[200*512]      @ 40960    (409600 B)
  //   Aswz    bf16[300*10*7168] @ 450560   (43,008,000 B)
  //   Bswz    bf16[20*10*32768] @ 43458560 (13,107,200 B)  => REQUIRED 56,565,760
  const size_t REQUIRED = 56565760ull;

  if (ws_size >= REQUIRED) {
    float* sinv = (float*)d_ws;
    float* ssqpart = (float*)((char*)d_ws + 40960);
    unsigned short* Aswz = (unsigned short*)((char*)d_ws + 450560);
    unsigned short* Bswz = (unsigned short*)((char*)d_ws + 43458560);
    dn4_prepA<<<TT * WQN * NKC, 256, 0, stream>>>(q, Aswz);
    dn4_prepB<<<TT * WAYN * NKC * SHOTN, 256, 0, stream>>>(s, Bswz, ssqpart);
    dn4_sinv2<<<TT * WAYN, 512, 0, stream>>>(ssqpart, sinv);
    dn4_main<<<TT * WAYN * WQN, 512, 0, stream>>>(Aswz, Bswz, sinv, out);
  } else {
    float* qinv = (float*)d_ws;
    float* sinv = (float*)((char*)d_ws + 768000);
    dn4_qinv<<<TT * WQN * CC / 4, 256, 0, stream>>>(q, qinv);
    dn4_sinv<<<TT * 25, 512, 0, stream>>>(s, sinv);
    dn4_main_fb<<<TT * WAYN * WQN, 512, 0, stream>>>(q, s, qinv, sinv, out);
  }
}